// Round 6
// baseline (200.037 us; speedup 1.0000x reference)
//
#include <hip/hip_runtime.h>
#include <math.h>

#define B_ 2
#define T_ 512
#define N_ 512
#define H_ 64
#define NBLK 512u

typedef _Float16 half8 __attribute__((ext_vector_type(8)));
typedef __attribute__((ext_vector_type(4))) float floatx4;

__device__ inline half8 habs8(half8 v) {
    union { half8 h; unsigned u[4]; } x; x.h = v;
    x.u[0] &= 0x7fff7fffu; x.u[1] &= 0x7fff7fffu;
    x.u[2] &= 0x7fff7fffu; x.u[3] &= 0x7fff7fffu;
    return x.h;
}

// Device-scope grid barrier. SAFETY: grid=512 blocks, __launch_bounds__(256,2)
// caps VGPR<=256 -> 2 blocks/CU x 256 CUs = all 512 co-resident. Deadman bound
// guarantees termination even if co-residency assumption breaks (fails
// correctness visibly instead of hanging the queue).
__device__ inline void grid_barrier(unsigned* cnt) {
    __syncthreads();                       // all waves drain vmem (vmcnt0) at s_barrier
    if (threadIdx.x == 0) {
        __threadfence();                   // release this block's writes device-wide
        __hip_atomic_fetch_add(cnt, 1u, __ATOMIC_ACQ_REL, __HIP_MEMORY_SCOPE_AGENT);
        unsigned spins = 0;
        while (__hip_atomic_load(cnt, __ATOMIC_ACQUIRE, __HIP_MEMORY_SCOPE_AGENT) < NBLK) {
            __builtin_amdgcn_s_sleep(2);
            if (++spins > (1u << 20)) break;   // deadman
        }
        __threadfence();                   // acquire: invalidate stale cached lines
    }
    __syncthreads();
}

// ---------------------------------------------------------------------------
// K1 (prep): 512 blocks.
//   all blocks   : dyn partials (B*8 n-chunks x 32 t-chunks)
//   blocks 0..31 : also W3[128:256] f16 pack in MFMA fragment order
//   block 0      : zeroes the 2 grid-barrier counters for K2
// ---------------------------------------------------------------------------
__global__ void prep_kernel(const float* __restrict__ x, const float* __restrict__ mask,
                            const float* __restrict__ W3,
                            float* __restrict__ part, _Float16* __restrict__ W3ph,
                            unsigned* __restrict__ cnt) {
    int blk = blockIdx.x;
    int b  = blk >> 8;
    int nc = (blk >> 5) & 7;
    int tc = blk & 31;
    int tn = threadIdx.x & 63;
    int tt = threadIdx.x >> 6;
    int n  = nc * 64 + tn;

    float sx = 0.f, sxx = 0.f, cnt_ = 0.f, msum = 0.f, bv = 0.f, bt = -1.f;
#pragma unroll
    for (int it = 0; it < 4; it++) {
        int t = tc * 16 + it * 4 + tt;
        int off = (b * T_ + t) * N_ + n;
        float xv = x[off];
        float mv = mask[off];
        float obs = 1.f - mv;
        sx   += xv * obs;
        sxx  += xv * xv * obs;
        cnt_ += obs;
        msum += mv;
        if (obs > 0.5f) { bt = (float)t; bv = xv; }
    }

    __shared__ float red[6][4][64];
    red[0][tt][tn] = sx;  red[1][tt][tn] = sxx; red[2][tt][tn] = cnt_;
    red[3][tt][tn] = msum; red[4][tt][tn] = bv; red[5][tt][tn] = bt;
    __syncthreads();

    if (threadIdx.x < 64) {
        float Sx = 0.f, Sxx = 0.f, Cnt = 0.f, Ms = 0.f, Bv = 0.f, Bt = -1.f;
#pragma unroll
        for (int u = 0; u < 4; u++) {
            Sx  += red[0][u][tn];
            Sxx += red[1][u][tn];
            Cnt += red[2][u][tn];
            Ms  += red[3][u][tn];
            float btu = red[5][u][tn];
            if (btu > Bt) { Bt = btu; Bv = red[4][u][tn]; }
        }
        const int plane = B_ * 32 * N_;
        int base = (b * 32 + tc) * N_ + n;
        part[0 * plane + base] = Sx;
        part[1 * plane + base] = Sxx;
        part[2 * plane + base] = Cnt;
        part[3 * plane + base] = Ms;
        part[4 * plane + base] = Bv;
        part[5 * plane + base] = Bt;
    }

    // W3 pack: W3p[((s*4+nt)*64+l)*8+t] = f16(W3[(128+s*32+(l>>4)*8+t)*64+nt*16+(l&15)])
    if (blk < 32) {
        int k = blk * 256 + threadIdx.x;   // 0..8191
        int t = k & 7;
        int l = (k >> 3) & 63;
        int f = k >> 9;
        int s = f >> 2, nt = f & 3;
        int quad = l >> 4, col = l & 15;
        W3ph[k] = (_Float16)W3[(128 + s * 32 + quad * 8 + t) * H_ + nt * 16 + col];
    }
    if (blk == 0 && threadIdx.x < 2) cnt[threadIdx.x] = 0u;
}

// ---------------------------------------------------------------------------
// K2 (mega): node MLP -> grid barrier -> pair MFMA -> grid barrier -> norm.
// 512 blocks x 256 threads, co-resident by construction.
// ---------------------------------------------------------------------------
__global__ __launch_bounds__(256, 2) void mega_kernel(
        const float* __restrict__ part, const float* __restrict__ x,
        const float* __restrict__ sc,
        const float* __restrict__ W1, const float* __restrict__ b1,
        const float* __restrict__ W2, const float* __restrict__ b2,
        const float* __restrict__ W3, const float* __restrict__ b3,
        const float* __restrict__ W4, const float* __restrict__ b4,
        const float* __restrict__ coords, const _Float16* __restrict__ W3ph,
        _Float16* __restrict__ nrh, float* __restrict__ P, float* __restrict__ Qp,
        float* __restrict__ adapt, float* __restrict__ degree,
        float* __restrict__ out, unsigned* __restrict__ cnt) {
    int tid = threadIdx.x;

    __shared__ union SMem {
        struct { float f[2][12]; float h[2][64]; float r[2][64]; } nb;
        struct { __align__(16) float sPrior[2][N_]; float sRow[2][4]; } pr;
    } sm;

    // ---------------- Phase B: node MLP (2 tasks x 64 thr; waves 2,3 idle) ---
    {
        int g = tid >> 6;                   // wave id 0..3
        int o = tid & 63;
        bool act = (g < 2);
        int gg = g & 1;
        int task = blockIdx.x * 2 + gg;     // 0..1023 (valid when act)
        int b = (task >> 9) & 1;
        int n = task & (N_ - 1);

        if (act) {
            const int plane = B_ * 32 * N_;
            float Sx = 0.f, Sxx = 0.f, Cnt = 0.f, Ms = 0.f, Bv = 0.f, Bt = -1.f;
            if (o < 32) {
                int base = (b * 32 + o) * N_ + n;
                Sx  = part[0 * plane + base];
                Sxx = part[1 * plane + base];
                Cnt = part[2 * plane + base];
                Ms  = part[3 * plane + base];
                Bv  = part[4 * plane + base];
                Bt  = part[5 * plane + base];
            }
#pragma unroll
            for (int off = 1; off < 32; off <<= 1) {
                Sx  += __shfl_xor(Sx, off);
                Sxx += __shfl_xor(Sxx, off);
                Cnt += __shfl_xor(Cnt, off);
                Ms  += __shfl_xor(Ms, off);
                float obt = __shfl_xor(Bt, off);
                float obv = __shfl_xor(Bv, off);
                if (obt > Bt) { Bt = obt; Bv = obv; }
            }
            if (o == 0) {
                float count = fmaxf(Cnt, 1.f);
                float mean  = Sx / count;
                float var   = (Sxx - 2.f * mean * Sx + mean * mean * Cnt) / count;
                float stdv  = sqrtf(fmaxf(var, 0.f) + 1e-6f);
                float last  = (Bt >= 0.f) ? Bv : x[b * T_ * N_ + n];
                sm.nb.f[gg][0] = mean; sm.nb.f[gg][1] = stdv;
                sm.nb.f[gg][2] = last; sm.nb.f[gg][3] = Ms * (1.f / (float)T_);
            }
            if (o >= 4 && o < 12) sm.nb.f[gg][o] = sc[n * 8 + (o - 4)];
        }
        __syncthreads();

        if (act) {
            float a = b1[o];
#pragma unroll
            for (int k = 0; k < 12; k++) a += sm.nb.f[gg][k] * W1[k * H_ + o];
            sm.nb.h[gg][o] = fmaxf(a, 0.f);
        }
        __syncthreads();

        if (act) {
            float a2 = b2[o];
#pragma unroll 8
            for (int k = 0; k < H_; k++) a2 += sm.nb.h[gg][k] * W2[k * H_ + o];
            float rv = fmaxf(a2, 0.f);
            sm.nb.r[gg][o] = rv;
            nrh[(b * N_ + n) * H_ + o] = (_Float16)rv;
        }
        __syncthreads();

        if (act) {
            float p = 0.f, q = 0.f;
#pragma unroll 8
            for (int k = 0; k < H_; k++) {
                float rk = sm.nb.r[gg][k];
                p += rk * W3[k * H_ + o];
                q += rk * W3[(H_ + k) * H_ + o];
            }
            P[(b * N_ + n) * H_ + o] = p;
            Qp[(b * N_ + n) * H_ + (o & 15) * 4 + (o >> 4)] = q;
        }
    }

    grid_barrier(&cnt[0]);

    // ---------------- Phase C: pair MFMA (round-4 verified structure) --------
    {
        int blk = blockIdx.x;
        int rb = blk >> 8;
        int ih = blk & 255;
        int i0 = ih * 2;
        int i1 = i0 + 1;
        int w = tid >> 6;
        int l = tid & 63;
        int col = l & 15;
        int quad = l >> 4;

        // prior rows i0, i1 -> LDS
#pragma unroll
        for (int s = 0; s < 2; s++) {
            int isel = i0 + s;
            float ci[8];
#pragma unroll
            for (int c = 0; c < 8; c++) ci[c] = coords[isel * 8 + c];
            for (int jj = tid; jj < N_; jj += 256) {
                float d2 = 0.f;
#pragma unroll
                for (int c = 0; c < 8; c++) {
                    float df = ci[c] - coords[jj * 8 + c];
                    d2 += df * df;
                }
                float dist = (d2 > 0.f) ? sqrtf(d2) : 0.f;
                sm.pr.sPrior[s][jj] = (jj == isel) ? 0.f : 1.f / (1.f + dist);
            }
        }

        half8 bf[4][4];
#pragma unroll
        for (int s = 0; s < 4; s++)
#pragma unroll
            for (int nt = 0; nt < 4; nt++)
                bf[s][nt] = *(const half8*)(W3ph + (((s * 4 + nt) * 64 + l) << 3));

        const _Float16* hi0_row = nrh + (rb * N_ + i0) * H_;
        const _Float16* hi1_row = nrh + (rb * N_ + i1) * H_;
        half8 hi0A = *(const half8*)(hi0_row + quad * 8);
        half8 hi0B = *(const half8*)(hi0_row + 32 + quad * 8);
        half8 hi1A = *(const half8*)(hi1_row + quad * 8);
        half8 hi1B = *(const half8*)(hi1_row + 32 + quad * 8);

        float pb30[4], pb31[4], w4v[4];
#pragma unroll
        for (int nt = 0; nt < 4; nt++) {
            int o = nt * 16 + col;
            float b3o = b3[o];
            pb30[nt] = P[(rb * N_ + i0) * H_ + o] + b3o;
            pb31[nt] = P[(rb * N_ + i1) * H_ + o] + b3o;
            w4v[nt] = W4[o];
        }
        float b4s = b4[0];
        const _Float16* nrb = nrh + (rb * N_) * H_;
        float rsum0 = 0.f, rsum1 = 0.f;
        __syncthreads();   // sPrior ready

        half8 hA, hB;
        {
            const _Float16* p0 = nrb + (w * 128 + col) * H_;
            hA = *(const half8*)(p0 + quad * 8);
            hB = *(const half8*)(p0 + 32 + quad * 8);
        }

#pragma unroll
        for (int mt = 0; mt < 8; mt++) {
            int j0 = w * 128 + mt * 16;

            half8 nA, nB;
            if (mt < 7) {
                const _Float16* pn = nrb + (j0 + 16 + col) * H_;
                nA = *(const half8*)(pn + quad * 8);
                nB = *(const half8*)(pn + 32 + quad * 8);
            }

            floatx4 pv0 = *(const floatx4*)(&sm.pr.sPrior[0][j0 + quad * 4]);
            floatx4 pv1 = *(const floatx4*)(&sm.pr.sPrior[1][j0 + quad * 4]);
            floatx4 qv[4];
#pragma unroll
            for (int r = 0; r < 4; r++)
                qv[r] = *(const floatx4*)(Qp + (rb * N_ + j0 + quad * 4 + r) * H_ + col * 4);

            // ---- row i0 ----
            {
                half8 dA = habs8(hi0A - hA);
                half8 dB = habs8(hi0B - hB);
                half8 mA = hi0A * hA;
                half8 mB = hi0B * hB;

                floatx4 acc[4];
#pragma unroll
                for (int nt = 0; nt < 4; nt++) acc[nt] = (floatx4){0.f, 0.f, 0.f, 0.f};
#pragma unroll
                for (int nt = 0; nt < 4; nt++) {
                    acc[nt] = __builtin_amdgcn_mfma_f32_16x16x32_f16(dA, bf[0][nt], acc[nt], 0, 0, 0);
                    acc[nt] = __builtin_amdgcn_mfma_f32_16x16x32_f16(dB, bf[1][nt], acc[nt], 0, 0, 0);
                    acc[nt] = __builtin_amdgcn_mfma_f32_16x16x32_f16(mA, bf[2][nt], acc[nt], 0, 0, 0);
                    acc[nt] = __builtin_amdgcn_mfma_f32_16x16x32_f16(mB, bf[3][nt], acc[nt], 0, 0, 0);
                }

                float ed[4];
#pragma unroll
                for (int r = 0; r < 4; r++) {
                    int j = j0 + quad * 4 + r;
                    float p = 0.f;
#pragma unroll
                    for (int nt = 0; nt < 4; nt++)
                        p += fmaxf(acc[nt][r] + pb30[nt] + qv[r][nt], 0.f) * w4v[nt];
                    p += __shfl_xor(p, 1);
                    p += __shfl_xor(p, 2);
                    p += __shfl_xor(p, 4);
                    p += __shfl_xor(p, 8);
                    float edge = fmaxf(p + b4s, 0.f);
                    float ad = (j == i0) ? 1.0f : edge * pv0[r];
                    ed[r] = ad;
                    rsum0 += ad;
                }
                if (col == 0) {
                    *(floatx4*)&adapt[(size_t)(rb * N_ + i0) * N_ + j0 + quad * 4] =
                        (floatx4){ed[0], ed[1], ed[2], ed[3]};
                }
            }

            // ---- row i1 ----
            {
                half8 dA = habs8(hi1A - hA);
                half8 dB = habs8(hi1B - hB);
                half8 mA = hi1A * hA;
                half8 mB = hi1B * hB;

                floatx4 acc[4];
#pragma unroll
                for (int nt = 0; nt < 4; nt++) acc[nt] = (floatx4){0.f, 0.f, 0.f, 0.f};
#pragma unroll
                for (int nt = 0; nt < 4; nt++) {
                    acc[nt] = __builtin_amdgcn_mfma_f32_16x16x32_f16(dA, bf[0][nt], acc[nt], 0, 0, 0);
                    acc[nt] = __builtin_amdgcn_mfma_f32_16x16x32_f16(dB, bf[1][nt], acc[nt], 0, 0, 0);
                    acc[nt] = __builtin_amdgcn_mfma_f32_16x16x32_f16(mA, bf[2][nt], acc[nt], 0, 0, 0);
                    acc[nt] = __builtin_amdgcn_mfma_f32_16x16x32_f16(mB, bf[3][nt], acc[nt], 0, 0, 0);
                }

                float ed[4];
#pragma unroll
                for (int r = 0; r < 4; r++) {
                    int j = j0 + quad * 4 + r;
                    float p = 0.f;
#pragma unroll
                    for (int nt = 0; nt < 4; nt++)
                        p += fmaxf(acc[nt][r] + pb31[nt] + qv[r][nt], 0.f) * w4v[nt];
                    p += __shfl_xor(p, 1);
                    p += __shfl_xor(p, 2);
                    p += __shfl_xor(p, 4);
                    p += __shfl_xor(p, 8);
                    float edge = fmaxf(p + b4s, 0.f);
                    float ad = (j == i1) ? 1.0f : edge * pv1[r];
                    ed[r] = ad;
                    rsum1 += ad;
                }
                if (col == 0) {
                    *(floatx4*)&adapt[(size_t)(rb * N_ + i1) * N_ + j0 + quad * 4] =
                        (floatx4){ed[0], ed[1], ed[2], ed[3]};
                }
            }

            if (mt < 7) { hA = nA; hB = nB; }
        }

        rsum0 += __shfl_xor(rsum0, 16);
        rsum0 += __shfl_xor(rsum0, 32);
        rsum1 += __shfl_xor(rsum1, 16);
        rsum1 += __shfl_xor(rsum1, 32);
        if (l == 0) { sm.pr.sRow[0][w] = rsum0; sm.pr.sRow[1][w] = rsum1; }
        __syncthreads();
        if (tid < 2)
            degree[rb * N_ + i0 + tid] =
                sm.pr.sRow[tid][0] + sm.pr.sRow[tid][1] + sm.pr.sRow[tid][2] + sm.pr.sRow[tid][3];
    }

    grid_barrier(&cnt[1]);

    // ---------------- Phase D: symmetric normalization -----------------------
    {
        int idx = blockIdx.x * 256 + tid;              // one float4 each
        int b = idx >> 16;
        int c4 = (idx & 127) << 2;
        float dr = rsqrtf(fmaxf(degree[b * N_ + ((idx >> 7) & (N_ - 1))], 1e-6f));
        floatx4 a = *(const floatx4*)(adapt + ((size_t)idx << 2));
        floatx4 o;
#pragma unroll
        for (int k = 0; k < 4; k++)
            o[k] = dr * a[k] * rsqrtf(fmaxf(degree[b * N_ + c4 + k], 1e-6f));
        *(floatx4*)(out + ((size_t)idx << 2)) = o;
    }
}

extern "C" void kernel_launch(void* const* d_in, const int* in_sizes, int n_in,
                              void* d_out, int out_size, void* d_ws, size_t ws_size,
                              hipStream_t stream) {
    const float* x      = (const float*)d_in[0];
    const float* mask   = (const float*)d_in[1];
    const float* sc     = (const float*)d_in[2];
    const float* coords = (const float*)d_in[3];
    const float* W1 = (const float*)d_in[4];
    const float* b1 = (const float*)d_in[5];
    const float* W2 = (const float*)d_in[6];
    const float* b2 = (const float*)d_in[7];
    const float* W3 = (const float*)d_in[8];
    const float* b3 = (const float*)d_in[9];
    const float* W4 = (const float*)d_in[10];
    const float* b4 = (const float*)d_in[11];
    float* out = (float*)d_out;

    // Layout (floats), total 889920 floats = 3.56 MB — below the 3.82 MB
    // footprint proven in-bounds by the round-0 kernel.
    float* wsp = (float*)d_ws;
    float* P       = wsp;                            // [0, 65536)
    float* Qp      = wsp + 65536;                    // [65536, 131072)
    _Float16* nrh  = (_Float16*)(wsp + 131072);      // 65536 halves = [131072,163840)
    _Float16* W3ph = (_Float16*)(wsp + 163840);      // 8192 halves  = [163840,167936)
    float* deg     = wsp + 167936;                   // [167936, 168960)
    unsigned* cnt  = (unsigned*)(wsp + 168960);      // 2 u32 (+pad)  [168960,169024)
    float* adapt   = wsp + 169024;                   // [169024, 693312)
    float* part    = wsp + 693312;                   // [693312, 889920)

    prep_kernel<<<512, 256, 0, stream>>>(x, mask, W3, part, W3ph, cnt);
    mega_kernel<<<512, 256, 0, stream>>>(part, x, sc, W1, b1, W2, b2, W3, b3, W4, b4,
                                         coords, W3ph, nrh, P, Qp, adapt, deg, out, cnt);
}

// Round 8
// 170.136 us; speedup vs baseline: 1.1757x; 1.1757x over previous
//
#include <hip/hip_runtime.h>
#include <math.h>

#define B_ 2
#define T_ 512
#define N_ 512
#define H_ 64
#define NBLK 512u

typedef _Float16 half8 __attribute__((ext_vector_type(8)));
typedef __attribute__((ext_vector_type(4))) float floatx4;

__device__ inline half8 habs8(half8 v) {
    union { half8 h; unsigned u[4]; } x; x.h = v;
    x.u[0] &= 0x7fff7fffu; x.u[1] &= 0x7fff7fffu;
    x.u[2] &= 0x7fff7fffu; x.u[3] &= 0x7fff7fffu;
    return x.h;
}

// Sense-reversing grid barrier. Arrivers fetch_add a counter; the LAST
// arriver release-stores `gen` into a separate flag word; others poll the
// flag with RELAXED agent loads (no per-poll cache invalidate, flag line
// written exactly once) + s_sleep backoff, then one ACQUIRE load for
// ordering. SAFETY: 512 blocks, launch_bounds(256,2) -> all co-resident;
// deadman bound terminates visibly on assumption failure.
__device__ inline void grid_barrier(unsigned* bar, unsigned* flag, unsigned gen) {
    __syncthreads();
    if (threadIdx.x == 0) {
        __threadfence();                   // release this block's writes
        unsigned old = __hip_atomic_fetch_add(bar, 1u, __ATOMIC_ACQ_REL,
                                              __HIP_MEMORY_SCOPE_AGENT);
        if (old == NBLK - 1u) {
            __hip_atomic_store(flag, gen, __ATOMIC_RELEASE, __HIP_MEMORY_SCOPE_AGENT);
        } else {
            unsigned spins = 0;
            while (__hip_atomic_load(flag, __ATOMIC_RELAXED,
                                     __HIP_MEMORY_SCOPE_AGENT) != gen) {
                __builtin_amdgcn_s_sleep(16);          // ~0.43 us backoff
                if (++spins > (1u << 17)) break;       // deadman ~56 ms
            }
            (void)__hip_atomic_load(flag, __ATOMIC_ACQUIRE, __HIP_MEMORY_SCOPE_AGENT);
        }
        __threadfence();                   // acquire side: discard stale lines
    }
    __syncthreads();
}

// ---------------------------------------------------------------------------
// K1 (prep): 512 blocks.
//   all blocks   : dyn partials (B*8 n-chunks x 32 t-chunks)
//   blocks 0..31 : also W3[128:256] f16 pack in MFMA fragment order
//   block 0      : zeroes the barrier counters/flag for K2
// ---------------------------------------------------------------------------
__global__ void prep_kernel(const float* __restrict__ x, const float* __restrict__ mask,
                            const float* __restrict__ W3,
                            float* __restrict__ part, _Float16* __restrict__ W3ph,
                            unsigned* __restrict__ cnt) {
    int blk = blockIdx.x;
    int b  = blk >> 8;
    int nc = (blk >> 5) & 7;
    int tc = blk & 31;
    int tn = threadIdx.x & 63;
    int tt = threadIdx.x >> 6;
    int n  = nc * 64 + tn;

    float sx = 0.f, sxx = 0.f, cnt_ = 0.f, msum = 0.f, bv = 0.f, bt = -1.f;
#pragma unroll
    for (int it = 0; it < 4; it++) {
        int t = tc * 16 + it * 4 + tt;
        int off = (b * T_ + t) * N_ + n;
        float xv = x[off];
        float mv = mask[off];
        float obs = 1.f - mv;
        sx   += xv * obs;
        sxx  += xv * xv * obs;
        cnt_ += obs;
        msum += mv;
        if (obs > 0.5f) { bt = (float)t; bv = xv; }
    }

    __shared__ float red[6][4][64];
    red[0][tt][tn] = sx;  red[1][tt][tn] = sxx; red[2][tt][tn] = cnt_;
    red[3][tt][tn] = msum; red[4][tt][tn] = bv; red[5][tt][tn] = bt;
    __syncthreads();

    if (threadIdx.x < 64) {
        float Sx = 0.f, Sxx = 0.f, Cnt = 0.f, Ms = 0.f, Bv = 0.f, Bt = -1.f;
#pragma unroll
        for (int u = 0; u < 4; u++) {
            Sx  += red[0][u][tn];
            Sxx += red[1][u][tn];
            Cnt += red[2][u][tn];
            Ms  += red[3][u][tn];
            float btu = red[5][u][tn];
            if (btu > Bt) { Bt = btu; Bv = red[4][u][tn]; }
        }
        const int plane = B_ * 32 * N_;
        int base = (b * 32 + tc) * N_ + n;
        part[0 * plane + base] = Sx;
        part[1 * plane + base] = Sxx;
        part[2 * plane + base] = Cnt;
        part[3 * plane + base] = Ms;
        part[4 * plane + base] = Bv;
        part[5 * plane + base] = Bt;
    }

    // W3 pack: W3p[((s*4+nt)*64+l)*8+t] = f16(W3[(128+s*32+(l>>4)*8+t)*64+nt*16+(l&15)])
    if (blk < 32) {
        int k = blk * 256 + threadIdx.x;   // 0..8191
        int t = k & 7;
        int l = (k >> 3) & 63;
        int f = k >> 9;
        int s = f >> 2, nt = f & 3;
        int quad = l >> 4, col = l & 15;
        W3ph[k] = (_Float16)W3[(128 + s * 32 + quad * 8 + t) * H_ + nt * 16 + col];
    }
    if (blk == 0 && threadIdx.x < 48) cnt[threadIdx.x] = 0u;  // cnt0, cnt1, flag (+pad)
}

// ---------------------------------------------------------------------------
// K2 (mega): node MLP -> grid barrier -> pair MFMA -> grid barrier -> norm.
// 512 blocks x 256 threads, co-resident by construction.
// ---------------------------------------------------------------------------
__global__ __launch_bounds__(256, 2) void mega_kernel(
        const float* __restrict__ part, const float* __restrict__ x,
        const float* __restrict__ sc,
        const float* __restrict__ W1, const float* __restrict__ b1,
        const float* __restrict__ W2, const float* __restrict__ b2,
        const float* __restrict__ W3, const float* __restrict__ b3,
        const float* __restrict__ W4, const float* __restrict__ b4,
        const float* __restrict__ coords, const _Float16* __restrict__ W3ph,
        _Float16* __restrict__ nrh, float* __restrict__ P, float* __restrict__ Qp,
        float* __restrict__ adapt, float* __restrict__ degree,
        float* __restrict__ out, unsigned* __restrict__ cnt) {
    int tid = threadIdx.x;

    __shared__ union SMem {
        struct { float f[2][12]; float h[2][64]; float r[2][64]; } nb;
        struct { __align__(16) float sPrior[2][N_]; float sRow[2][4]; } pr;
    } sm;

    // ---------------- Phase B: node MLP (2 tasks x 64 thr; waves 2,3 idle) ---
    {
        int g = tid >> 6;                   // wave id 0..3
        int o = tid & 63;
        bool act = (g < 2);
        int gg = g & 1;
        int task = blockIdx.x * 2 + gg;     // 0..1023 (valid when act)
        int b = (task >> 9) & 1;
        int n = task & (N_ - 1);

        if (act) {
            const int plane = B_ * 32 * N_;
            float Sx = 0.f, Sxx = 0.f, Cnt = 0.f, Ms = 0.f, Bv = 0.f, Bt = -1.f;
            if (o < 32) {
                int base = (b * 32 + o) * N_ + n;
                Sx  = part[0 * plane + base];
                Sxx = part[1 * plane + base];
                Cnt = part[2 * plane + base];
                Ms  = part[3 * plane + base];
                Bv  = part[4 * plane + base];
                Bt  = part[5 * plane + base];
            }
#pragma unroll
            for (int off = 1; off < 32; off <<= 1) {
                Sx  += __shfl_xor(Sx, off);
                Sxx += __shfl_xor(Sxx, off);
                Cnt += __shfl_xor(Cnt, off);
                Ms  += __shfl_xor(Ms, off);
                float obt = __shfl_xor(Bt, off);
                float obv = __shfl_xor(Bv, off);
                if (obt > Bt) { Bt = obt; Bv = obv; }
            }
            if (o == 0) {
                float count = fmaxf(Cnt, 1.f);
                float mean  = Sx / count;
                float var   = (Sxx - 2.f * mean * Sx + mean * mean * Cnt) / count;
                float stdv  = sqrtf(fmaxf(var, 0.f) + 1e-6f);
                float last  = (Bt >= 0.f) ? Bv : x[b * T_ * N_ + n];
                sm.nb.f[gg][0] = mean; sm.nb.f[gg][1] = stdv;
                sm.nb.f[gg][2] = last; sm.nb.f[gg][3] = Ms * (1.f / (float)T_);
            }
            if (o >= 4 && o < 12) sm.nb.f[gg][o] = sc[n * 8 + (o - 4)];
        }
        __syncthreads();

        if (act) {
            float a = b1[o];
#pragma unroll
            for (int k = 0; k < 12; k++) a += sm.nb.f[gg][k] * W1[k * H_ + o];
            sm.nb.h[gg][o] = fmaxf(a, 0.f);
        }
        __syncthreads();

        if (act) {
            float a2 = b2[o];
#pragma unroll 8
            for (int k = 0; k < H_; k++) a2 += sm.nb.h[gg][k] * W2[k * H_ + o];
            float rv = fmaxf(a2, 0.f);
            sm.nb.r[gg][o] = rv;
            nrh[(b * N_ + n) * H_ + o] = (_Float16)rv;
        }
        __syncthreads();

        if (act) {
            float p = 0.f, q = 0.f;
#pragma unroll 8
            for (int k = 0; k < H_; k++) {
                float rk = sm.nb.r[gg][k];
                p += rk * W3[k * H_ + o];
                q += rk * W3[(H_ + k) * H_ + o];
            }
            P[(b * N_ + n) * H_ + o] = p;
            Qp[(b * N_ + n) * H_ + (o & 15) * 4 + (o >> 4)] = q;
        }
    }

    grid_barrier(&cnt[0], &cnt[32], 1u);

    // ---------------- Phase C: pair MFMA (round-4 verified structure) --------
    {
        int blk = blockIdx.x;
        int rb = blk >> 8;
        int ih = blk & 255;
        int i0 = ih * 2;
        int i1 = i0 + 1;
        int w = tid >> 6;
        int l = tid & 63;
        int col = l & 15;
        int quad = l >> 4;

        // prior rows i0, i1 -> LDS
#pragma unroll
        for (int s = 0; s < 2; s++) {
            int isel = i0 + s;
            float ci[8];
#pragma unroll
            for (int c = 0; c < 8; c++) ci[c] = coords[isel * 8 + c];
            for (int jj = tid; jj < N_; jj += 256) {
                float d2 = 0.f;
#pragma unroll
                for (int c = 0; c < 8; c++) {
                    float df = ci[c] - coords[jj * 8 + c];
                    d2 += df * df;
                }
                float dist = (d2 > 0.f) ? sqrtf(d2) : 0.f;
                sm.pr.sPrior[s][jj] = (jj == isel) ? 0.f : 1.f / (1.f + dist);
            }
        }

        half8 bf[4][4];
#pragma unroll
        for (int s = 0; s < 4; s++)
#pragma unroll
            for (int nt = 0; nt < 4; nt++)
                bf[s][nt] = *(const half8*)(W3ph + (((s * 4 + nt) * 64 + l) << 3));

        const _Float16* hi0_row = nrh + (rb * N_ + i0) * H_;
        const _Float16* hi1_row = nrh + (rb * N_ + i1) * H_;
        half8 hi0A = *(const half8*)(hi0_row + quad * 8);
        half8 hi0B = *(const half8*)(hi0_row + 32 + quad * 8);
        half8 hi1A = *(const half8*)(hi1_row + quad * 8);
        half8 hi1B = *(const half8*)(hi1_row + 32 + quad * 8);

        float pb30[4], pb31[4], w4v[4];
#pragma unroll
        for (int nt = 0; nt < 4; nt++) {
            int o = nt * 16 + col;
            float b3o = b3[o];
            pb30[nt] = P[(rb * N_ + i0) * H_ + o] + b3o;
            pb31[nt] = P[(rb * N_ + i1) * H_ + o] + b3o;
            w4v[nt] = W4[o];
        }
        float b4s = b4[0];
        const _Float16* nrb = nrh + (rb * N_) * H_;
        float rsum0 = 0.f, rsum1 = 0.f;
        __syncthreads();   // sPrior ready

        half8 hA, hB;
        {
            const _Float16* p0 = nrb + (w * 128 + col) * H_;
            hA = *(const half8*)(p0 + quad * 8);
            hB = *(const half8*)(p0 + 32 + quad * 8);
        }

#pragma unroll
        for (int mt = 0; mt < 8; mt++) {
            int j0 = w * 128 + mt * 16;

            half8 nA, nB;
            if (mt < 7) {
                const _Float16* pn = nrb + (j0 + 16 + col) * H_;
                nA = *(const half8*)(pn + quad * 8);
                nB = *(const half8*)(pn + 32 + quad * 8);
            }

            floatx4 pv0 = *(const floatx4*)(&sm.pr.sPrior[0][j0 + quad * 4]);
            floatx4 pv1 = *(const floatx4*)(&sm.pr.sPrior[1][j0 + quad * 4]);
            floatx4 qv[4];
#pragma unroll
            for (int r = 0; r < 4; r++)
                qv[r] = *(const floatx4*)(Qp + (rb * N_ + j0 + quad * 4 + r) * H_ + col * 4);

            // ---- row i0 ----
            {
                half8 dA = habs8(hi0A - hA);
                half8 dB = habs8(hi0B - hB);
                half8 mA = hi0A * hA;
                half8 mB = hi0B * hB;

                floatx4 acc[4];
#pragma unroll
                for (int nt = 0; nt < 4; nt++) acc[nt] = (floatx4){0.f, 0.f, 0.f, 0.f};
#pragma unroll
                for (int nt = 0; nt < 4; nt++) {
                    acc[nt] = __builtin_amdgcn_mfma_f32_16x16x32_f16(dA, bf[0][nt], acc[nt], 0, 0, 0);
                    acc[nt] = __builtin_amdgcn_mfma_f32_16x16x32_f16(dB, bf[1][nt], acc[nt], 0, 0, 0);
                    acc[nt] = __builtin_amdgcn_mfma_f32_16x16x32_f16(mA, bf[2][nt], acc[nt], 0, 0, 0);
                    acc[nt] = __builtin_amdgcn_mfma_f32_16x16x32_f16(mB, bf[3][nt], acc[nt], 0, 0, 0);
                }

                float ed[4];
#pragma unroll
                for (int r = 0; r < 4; r++) {
                    int j = j0 + quad * 4 + r;
                    float p = 0.f;
#pragma unroll
                    for (int nt = 0; nt < 4; nt++)
                        p += fmaxf(acc[nt][r] + pb30[nt] + qv[r][nt], 0.f) * w4v[nt];
                    p += __shfl_xor(p, 1);
                    p += __shfl_xor(p, 2);
                    p += __shfl_xor(p, 4);
                    p += __shfl_xor(p, 8);
                    float edge = fmaxf(p + b4s, 0.f);
                    float ad = (j == i0) ? 1.0f : edge * pv0[r];
                    ed[r] = ad;
                    rsum0 += ad;
                }
                if (col == 0) {
                    *(floatx4*)&adapt[(size_t)(rb * N_ + i0) * N_ + j0 + quad * 4] =
                        (floatx4){ed[0], ed[1], ed[2], ed[3]};
                }
            }

            // ---- row i1 ----
            {
                half8 dA = habs8(hi1A - hA);
                half8 dB = habs8(hi1B - hB);
                half8 mA = hi1A * hA;
                half8 mB = hi1B * hB;

                floatx4 acc[4];
#pragma unroll
                for (int nt = 0; nt < 4; nt++) acc[nt] = (floatx4){0.f, 0.f, 0.f, 0.f};
#pragma unroll
                for (int nt = 0; nt < 4; nt++) {
                    acc[nt] = __builtin_amdgcn_mfma_f32_16x16x32_f16(dA, bf[0][nt], acc[nt], 0, 0, 0);
                    acc[nt] = __builtin_amdgcn_mfma_f32_16x16x32_f16(dB, bf[1][nt], acc[nt], 0, 0, 0);
                    acc[nt] = __builtin_amdgcn_mfma_f32_16x16x32_f16(mA, bf[2][nt], acc[nt], 0, 0, 0);
                    acc[nt] = __builtin_amdgcn_mfma_f32_16x16x32_f16(mB, bf[3][nt], acc[nt], 0, 0, 0);
                }

                float ed[4];
#pragma unroll
                for (int r = 0; r < 4; r++) {
                    int j = j0 + quad * 4 + r;
                    float p = 0.f;
#pragma unroll
                    for (int nt = 0; nt < 4; nt++)
                        p += fmaxf(acc[nt][r] + pb31[nt] + qv[r][nt], 0.f) * w4v[nt];
                    p += __shfl_xor(p, 1);
                    p += __shfl_xor(p, 2);
                    p += __shfl_xor(p, 4);
                    p += __shfl_xor(p, 8);
                    float edge = fmaxf(p + b4s, 0.f);
                    float ad = (j == i1) ? 1.0f : edge * pv1[r];
                    ed[r] = ad;
                    rsum1 += ad;
                }
                if (col == 0) {
                    *(floatx4*)&adapt[(size_t)(rb * N_ + i1) * N_ + j0 + quad * 4] =
                        (floatx4){ed[0], ed[1], ed[2], ed[3]};
                }
            }

            if (mt < 7) { hA = nA; hB = nB; }
        }

        rsum0 += __shfl_xor(rsum0, 16);
        rsum0 += __shfl_xor(rsum0, 32);
        rsum1 += __shfl_xor(rsum1, 16);
        rsum1 += __shfl_xor(rsum1, 32);
        if (l == 0) { sm.pr.sRow[0][w] = rsum0; sm.pr.sRow[1][w] = rsum1; }
        __syncthreads();
        if (tid < 2)
            degree[rb * N_ + i0 + tid] =
                sm.pr.sRow[tid][0] + sm.pr.sRow[tid][1] + sm.pr.sRow[tid][2] + sm.pr.sRow[tid][3];
    }

    grid_barrier(&cnt[1], &cnt[32], 2u);

    // ---------------- Phase D: symmetric normalization -----------------------
    {
        int idx = blockIdx.x * 256 + tid;              // one float4 each
        int b = idx >> 16;
        int c4 = (idx & 127) << 2;
        float dr = rsqrtf(fmaxf(degree[b * N_ + ((idx >> 7) & (N_ - 1))], 1e-6f));
        floatx4 a = *(const floatx4*)(adapt + ((size_t)idx << 2));
        floatx4 o;
#pragma unroll
        for (int k = 0; k < 4; k++)
            o[k] = dr * a[k] * rsqrtf(fmaxf(degree[b * N_ + c4 + k], 1e-6f));
        *(floatx4*)(out + ((size_t)idx << 2)) = o;
    }
}

extern "C" void kernel_launch(void* const* d_in, const int* in_sizes, int n_in,
                              void* d_out, int out_size, void* d_ws, size_t ws_size,
                              hipStream_t stream) {
    const float* x      = (const float*)d_in[0];
    const float* mask   = (const float*)d_in[1];
    const float* sc     = (const float*)d_in[2];
    const float* coords = (const float*)d_in[3];
    const float* W1 = (const float*)d_in[4];
    const float* b1 = (const float*)d_in[5];
    const float* W2 = (const float*)d_in[6];
    const float* b2 = (const float*)d_in[7];
    const float* W3 = (const float*)d_in[8];
    const float* b3 = (const float*)d_in[9];
    const float* W4 = (const float*)d_in[10];
    const float* b4 = (const float*)d_in[11];
    float* out = (float*)d_out;

    // Layout (floats), total 889984 floats = 3.56 MB — below the 3.82 MB
    // footprint proven in-bounds by the round-0 kernel.
    float* wsp = (float*)d_ws;
    float* P       = wsp;                            // [0, 65536)
    float* Qp      = wsp + 65536;                    // [65536, 131072)
    _Float16* nrh  = (_Float16*)(wsp + 131072);      // 65536 halves = [131072,163840)
    _Float16* W3ph = (_Float16*)(wsp + 163840);      // 8192 halves  = [163840,167936)
    float* deg     = wsp + 167936;                   // [167936, 168960)
    unsigned* cnt  = (unsigned*)(wsp + 168960);      // 48 u32: cnt0, cnt1, flag@+32
    float* adapt   = wsp + 169088;                   // [169088, 693376)
    float* part    = wsp + 693376;                   // [693376, 889984)

    prep_kernel<<<512, 256, 0, stream>>>(x, mask, W3, part, W3ph, cnt);
    mega_kernel<<<512, 256, 0, stream>>>(part, x, sc, W1, b1, W2, b2, W3, b3, W4, b4,
                                         coords, W3ph, nrh, P, Qp, adapt, deg, out, cnt);
}

// Round 9
// 107.327 us; speedup vs baseline: 1.8638x; 1.5852x over previous
//
#include <hip/hip_runtime.h>
#include <math.h>

#define B_ 2
#define T_ 512
#define N_ 512
#define H_ 64

typedef _Float16 half8 __attribute__((ext_vector_type(8)));
typedef __attribute__((ext_vector_type(4))) float floatx4;

__device__ inline half8 habs8(half8 v) {
    union { half8 h; unsigned u[4]; } x; x.h = v;
    x.u[0] &= 0x7fff7fffu; x.u[1] &= 0x7fff7fffu;
    x.u[2] &= 0x7fff7fffu; x.u[3] &= 0x7fff7fffu;
    return x.h;
}

// Sum over each 16-lane row via DPP (VALU pipe, no DS ops).
// Steps: quad_perm[1,0,3,2] (xor1), quad_perm[2,3,0,1] (xor2) -> quad sums;
// row_ror:4 + row_ror:8 -> every lane holds the 16-lane total.
__device__ inline float dpp_sum16(float v) {
    int t;
    t = __builtin_amdgcn_update_dpp(0, __float_as_int(v), 0xB1, 0xF, 0xF, true);
    v += __int_as_float(t);
    t = __builtin_amdgcn_update_dpp(0, __float_as_int(v), 0x4E, 0xF, 0xF, true);
    v += __int_as_float(t);
    t = __builtin_amdgcn_update_dpp(0, __float_as_int(v), 0x124, 0xF, 0xF, true);
    v += __int_as_float(t);
    t = __builtin_amdgcn_update_dpp(0, __float_as_int(v), 0x128, 0xF, 0xF, true);
    v += __int_as_float(t);
    return v;
}

// ---------------------------------------------------------------------------
// Kernel 1 (fused prep): grid-partitioned independent work.
//   blocks 0..511   : dyn partials (B*8 n-chunks x 32 t-chunks)
//   blocks 512..543 : W3[128:256] f16 pack in MFMA fragment order
// ---------------------------------------------------------------------------
__global__ void prep_kernel(const float* __restrict__ x, const float* __restrict__ mask,
                            const float* __restrict__ W3,
                            float* __restrict__ part, _Float16* __restrict__ W3ph) {
    int blk = blockIdx.x;
    if (blk < 512) {
        int b  = blk >> 8;
        int nc = (blk >> 5) & 7;
        int tc = blk & 31;
        int tn = threadIdx.x & 63;
        int tt = threadIdx.x >> 6;
        int n  = nc * 64 + tn;

        float sx = 0.f, sxx = 0.f, cnt = 0.f, msum = 0.f, bv = 0.f, bt = -1.f;
#pragma unroll
        for (int it = 0; it < 4; it++) {
            int t = tc * 16 + it * 4 + tt;
            int off = (b * T_ + t) * N_ + n;
            float xv = x[off];
            float mv = mask[off];
            float obs = 1.f - mv;
            sx   += xv * obs;
            sxx  += xv * xv * obs;
            cnt  += obs;
            msum += mv;
            if (obs > 0.5f) { bt = (float)t; bv = xv; }
        }

        __shared__ float red[6][4][64];
        red[0][tt][tn] = sx;  red[1][tt][tn] = sxx; red[2][tt][tn] = cnt;
        red[3][tt][tn] = msum; red[4][tt][tn] = bv; red[5][tt][tn] = bt;
        __syncthreads();

        if (threadIdx.x < 64) {
            float Sx = 0.f, Sxx = 0.f, Cnt = 0.f, Ms = 0.f, Bv = 0.f, Bt = -1.f;
#pragma unroll
            for (int u = 0; u < 4; u++) {
                Sx  += red[0][u][tn];
                Sxx += red[1][u][tn];
                Cnt += red[2][u][tn];
                Ms  += red[3][u][tn];
                float btu = red[5][u][tn];
                if (btu > Bt) { Bt = btu; Bv = red[4][u][tn]; }
            }
            const int plane = B_ * 32 * N_;
            int base = (b * 32 + tc) * N_ + n;
            part[0 * plane + base] = Sx;
            part[1 * plane + base] = Sxx;
            part[2 * plane + base] = Cnt;
            part[3 * plane + base] = Ms;
            part[4 * plane + base] = Bv;
            part[5 * plane + base] = Bt;
        }
    } else {
        // W3p[((s*4+nt)*64+l)*8+t] = f16(W3[(128+s*32+(l>>4)*8+t)*64 + nt*16+(l&15)])
        int k = (blk - 512) * 256 + threadIdx.x;   // 0..8191
        int t = k & 7;
        int l = (k >> 3) & 63;
        int f = k >> 9;
        int s = f >> 2, nt = f & 3;
        int quad = l >> 4, col = l & 15;
        W3ph[k] = (_Float16)W3[(128 + s * 32 + quad * 8 + t) * H_ + nt * 16 + col];
    }
}

// ---------------------------------------------------------------------------
// Kernel 2 (fused): dyn final reduce + node MLP (12->64->64) -> nrh (f16),
// P = r@W3[0:64], Qp = permuted r@W3[64:128]. One 64-thr block per (b,n).
// ---------------------------------------------------------------------------
__global__ __launch_bounds__(64) void node_kernel(
        const float* __restrict__ part, const float* __restrict__ x,
        const float* __restrict__ sc,
        const float* __restrict__ W1, const float* __restrict__ b1,
        const float* __restrict__ W2, const float* __restrict__ b2,
        const float* __restrict__ W3,
        _Float16* __restrict__ nrh, float* __restrict__ P, float* __restrict__ Qp) {
    int blk = blockIdx.x;
    int b = blk >> 9;
    int n = blk & (N_ - 1);
    int o = threadIdx.x;

    __shared__ float f[12];
    __shared__ float h[H_];
    __shared__ float r[H_];

    {
        const int plane = B_ * 32 * N_;
        float Sx = 0.f, Sxx = 0.f, Cnt = 0.f, Ms = 0.f, Bv = 0.f, Bt = -1.f;
        if (o < 32) {
            int base = (b * 32 + o) * N_ + n;
            Sx  = part[0 * plane + base];
            Sxx = part[1 * plane + base];
            Cnt = part[2 * plane + base];
            Ms  = part[3 * plane + base];
            Bv  = part[4 * plane + base];
            Bt  = part[5 * plane + base];
        }
#pragma unroll
        for (int off = 1; off < 32; off <<= 1) {
            Sx  += __shfl_xor(Sx, off);
            Sxx += __shfl_xor(Sxx, off);
            Cnt += __shfl_xor(Cnt, off);
            Ms  += __shfl_xor(Ms, off);
            float obt = __shfl_xor(Bt, off);
            float obv = __shfl_xor(Bv, off);
            if (obt > Bt) { Bt = obt; Bv = obv; }
        }
        if (o == 0) {
            float count = fmaxf(Cnt, 1.f);
            float mean  = Sx / count;
            float var   = (Sxx - 2.f * mean * Sx + mean * mean * Cnt) / count;
            float stdv  = sqrtf(fmaxf(var, 0.f) + 1e-6f);
            float last  = (Bt >= 0.f) ? Bv : x[b * T_ * N_ + n];
            f[0] = mean; f[1] = stdv; f[2] = last; f[3] = Ms * (1.f / (float)T_);
        }
        if (o >= 4 && o < 12) f[o] = sc[n * 8 + (o - 4)];
    }
    __syncthreads();

    float a = b1[o];
#pragma unroll
    for (int k = 0; k < 12; k++) a += f[k] * W1[k * H_ + o];
    h[o] = fmaxf(a, 0.f);
    __syncthreads();

    float a2 = b2[o];
#pragma unroll 8
    for (int k = 0; k < H_; k++) a2 += h[k] * W2[k * H_ + o];
    float rv = fmaxf(a2, 0.f);
    r[o] = rv;
    nrh[(b * N_ + n) * H_ + o] = (_Float16)rv;
    __syncthreads();

    float p = 0.f, q = 0.f;
#pragma unroll 8
    for (int k = 0; k < H_; k++) {
        float rk = r[k];
        p += rk * W3[k * H_ + o];
        q += rk * W3[(H_ + k) * H_ + o];
    }
    P[(b * N_ + n) * H_ + o] = p;
    Qp[(b * N_ + n) * H_ + (o & 15) * 4 + (o >> 4)] = q;
}

// ---------------------------------------------------------------------------
// Kernel 3 (MFMA, packed f16): one block per (rb, i-pair). Rows i0=2*ih,
// i1=i0+1 share hj-tile/Qp loads and bf fragments. Epilogue 16-lane
// reductions use DPP VALU adds (dpp_sum16) instead of DS shuffles.
// ---------------------------------------------------------------------------
__global__ __launch_bounds__(256) void pair_mfma_kernel(
        const _Float16* __restrict__ nrh, const float* __restrict__ P,
        const float* __restrict__ Qp, const _Float16* __restrict__ W3ph,
        const float* __restrict__ coords,
        const float* __restrict__ b3, const float* __restrict__ W4,
        const float* __restrict__ b4,
        float* __restrict__ adapt, float* __restrict__ degree) {
    int blk = blockIdx.x;
    int rb = blk >> 8;                  // batch 0..1
    int ih = blk & 255;
    int i0 = ih * 2;
    int i1 = i0 + 1;
    int tid = threadIdx.x;
    int w = tid >> 6;
    int l = tid & 63;
    int col = l & 15;
    int quad = l >> 4;

    __shared__ __align__(16) float sPrior[2][N_];
    __shared__ float sRow[2][4];

    // prior rows i0, i1 -> LDS
#pragma unroll
    for (int s = 0; s < 2; s++) {
        int isel = i0 + s;
        float ci[8];
#pragma unroll
        for (int c = 0; c < 8; c++) ci[c] = coords[isel * 8 + c];
        for (int jj = tid; jj < N_; jj += 256) {
            float d2 = 0.f;
#pragma unroll
            for (int c = 0; c < 8; c++) {
                float df = ci[c] - coords[jj * 8 + c];
                d2 += df * df;
            }
            float dist = (d2 > 0.f) ? sqrtf(d2) : 0.f;
            sPrior[s][jj] = (jj == isel) ? 0.f : 1.f / (1.f + dist);
        }
    }

    // B fragments: one 16B load each, pre-packed in fragment order
    half8 bf[4][4];
#pragma unroll
    for (int s = 0; s < 4; s++)
#pragma unroll
        for (int nt = 0; nt < 4; nt++)
            bf[s][nt] = *(const half8*)(W3ph + (((s * 4 + nt) * 64 + l) << 3));

    const _Float16* hi0_row = nrh + (rb * N_ + i0) * H_;
    const _Float16* hi1_row = nrh + (rb * N_ + i1) * H_;
    half8 hi0A = *(const half8*)(hi0_row + quad * 8);
    half8 hi0B = *(const half8*)(hi0_row + 32 + quad * 8);
    half8 hi1A = *(const half8*)(hi1_row + quad * 8);
    half8 hi1B = *(const half8*)(hi1_row + 32 + quad * 8);

    float pb30[4], pb31[4], w4v[4];
#pragma unroll
    for (int nt = 0; nt < 4; nt++) {
        int o = nt * 16 + col;
        float b3o = b3[o];
        pb30[nt] = P[(rb * N_ + i0) * H_ + o] + b3o;
        pb31[nt] = P[(rb * N_ + i1) * H_ + o] + b3o;
        w4v[nt] = W4[o];
    }
    float b4s = b4[0];
    const _Float16* nrb = nrh + (rb * N_) * H_;
    float rsum0 = 0.f, rsum1 = 0.f;
    __syncthreads();   // sPrior ready

    // prefetch tile 0
    half8 hA, hB;
    {
        const _Float16* p0 = nrb + (w * 128 + col) * H_;
        hA = *(const half8*)(p0 + quad * 8);
        hB = *(const half8*)(p0 + 32 + quad * 8);
    }

#pragma unroll
    for (int mt = 0; mt < 8; mt++) {
        int j0 = w * 128 + mt * 16;

        // prefetch next hj tile
        half8 nA, nB;
        if (mt < 7) {
            const _Float16* pn = nrb + (j0 + 16 + col) * H_;
            nA = *(const half8*)(pn + quad * 8);
            nB = *(const half8*)(pn + 32 + quad * 8);
        }

        // shared epilogue operands (issued early, hide latency under MFMA)
        floatx4 pv0 = *(const floatx4*)(&sPrior[0][j0 + quad * 4]);
        floatx4 pv1 = *(const floatx4*)(&sPrior[1][j0 + quad * 4]);
        floatx4 qv[4];
#pragma unroll
        for (int r = 0; r < 4; r++)
            qv[r] = *(const floatx4*)(Qp + (rb * N_ + j0 + quad * 4 + r) * H_ + col * 4);

        // ---- row i0 ----
        {
            half8 dA = habs8(hi0A - hA);
            half8 dB = habs8(hi0B - hB);
            half8 mA = hi0A * hA;
            half8 mB = hi0B * hB;

            floatx4 acc[4];
#pragma unroll
            for (int nt = 0; nt < 4; nt++) acc[nt] = (floatx4){0.f, 0.f, 0.f, 0.f};
#pragma unroll
            for (int nt = 0; nt < 4; nt++) {
                acc[nt] = __builtin_amdgcn_mfma_f32_16x16x32_f16(dA, bf[0][nt], acc[nt], 0, 0, 0);
                acc[nt] = __builtin_amdgcn_mfma_f32_16x16x32_f16(dB, bf[1][nt], acc[nt], 0, 0, 0);
                acc[nt] = __builtin_amdgcn_mfma_f32_16x16x32_f16(mA, bf[2][nt], acc[nt], 0, 0, 0);
                acc[nt] = __builtin_amdgcn_mfma_f32_16x16x32_f16(mB, bf[3][nt], acc[nt], 0, 0, 0);
            }

            float ed[4];
#pragma unroll
            for (int r = 0; r < 4; r++) {
                int j = j0 + quad * 4 + r;
                float p = 0.f;
#pragma unroll
                for (int nt = 0; nt < 4; nt++)
                    p += fmaxf(acc[nt][r] + pb30[nt] + qv[r][nt], 0.f) * w4v[nt];
                p = dpp_sum16(p);
                float edge = fmaxf(p + b4s, 0.f);
                float ad = (j == i0) ? 1.0f : edge * pv0[r];
                ed[r] = ad;
                rsum0 += ad;
            }
            if (col == 0) {
                *(floatx4*)&adapt[(size_t)(rb * N_ + i0) * N_ + j0 + quad * 4] =
                    (floatx4){ed[0], ed[1], ed[2], ed[3]};
            }
        }

        // ---- row i1 ----
        {
            half8 dA = habs8(hi1A - hA);
            half8 dB = habs8(hi1B - hB);
            half8 mA = hi1A * hA;
            half8 mB = hi1B * hB;

            floatx4 acc[4];
#pragma unroll
            for (int nt = 0; nt < 4; nt++) acc[nt] = (floatx4){0.f, 0.f, 0.f, 0.f};
#pragma unroll
            for (int nt = 0; nt < 4; nt++) {
                acc[nt] = __builtin_amdgcn_mfma_f32_16x16x32_f16(dA, bf[0][nt], acc[nt], 0, 0, 0);
                acc[nt] = __builtin_amdgcn_mfma_f32_16x16x32_f16(dB, bf[1][nt], acc[nt], 0, 0, 0);
                acc[nt] = __builtin_amdgcn_mfma_f32_16x16x32_f16(mA, bf[2][nt], acc[nt], 0, 0, 0);
                acc[nt] = __builtin_amdgcn_mfma_f32_16x16x32_f16(mB, bf[3][nt], acc[nt], 0, 0, 0);
            }

            float ed[4];
#pragma unroll
            for (int r = 0; r < 4; r++) {
                int j = j0 + quad * 4 + r;
                float p = 0.f;
#pragma unroll
                for (int nt = 0; nt < 4; nt++)
                    p += fmaxf(acc[nt][r] + pb31[nt] + qv[r][nt], 0.f) * w4v[nt];
                p = dpp_sum16(p);
                float edge = fmaxf(p + b4s, 0.f);
                float ad = (j == i1) ? 1.0f : edge * pv1[r];
                ed[r] = ad;
                rsum1 += ad;
            }
            if (col == 0) {
                *(floatx4*)&adapt[(size_t)(rb * N_ + i1) * N_ + j0 + quad * 4] =
                    (floatx4){ed[0], ed[1], ed[2], ed[3]};
            }
        }

        if (mt < 7) { hA = nA; hB = nB; }
    }

    rsum0 += __shfl_xor(rsum0, 16);
    rsum0 += __shfl_xor(rsum0, 32);
    rsum1 += __shfl_xor(rsum1, 16);
    rsum1 += __shfl_xor(rsum1, 32);
    if (l == 0) { sRow[0][w] = rsum0; sRow[1][w] = rsum1; }
    __syncthreads();
    if (tid < 2)
        degree[rb * N_ + i0 + tid] = sRow[tid][0] + sRow[tid][1] + sRow[tid][2] + sRow[tid][3];
}

// ---------------------------------------------------------------------------
// Kernel 4: symmetric normalization out = D^-1/2 A D^-1/2 (float4)
// ---------------------------------------------------------------------------
__global__ void norm_kernel(const float* __restrict__ adapt, const float* __restrict__ deg,
                            float* __restrict__ out) {
    int idx = blockIdx.x * 256 + threadIdx.x;      // one float4 each
    int b = idx >> 16;
    int r = (idx >> 7) & (N_ - 1);
    int c4 = (idx & 127) << 2;
    float dr = rsqrtf(fmaxf(deg[b * N_ + r], 1e-6f));
    floatx4 a = *(const floatx4*)(adapt + ((size_t)idx << 2));
    floatx4 o;
#pragma unroll
    for (int k = 0; k < 4; k++)
        o[k] = dr * a[k] * rsqrtf(fmaxf(deg[b * N_ + c4 + k], 1e-6f));
    *(floatx4*)(out + ((size_t)idx << 2)) = o;
}

extern "C" void kernel_launch(void* const* d_in, const int* in_sizes, int n_in,
                              void* d_out, int out_size, void* d_ws, size_t ws_size,
                              hipStream_t stream) {
    const float* x      = (const float*)d_in[0];
    const float* mask   = (const float*)d_in[1];
    const float* sc     = (const float*)d_in[2];
    const float* coords = (const float*)d_in[3];
    const float* W1 = (const float*)d_in[4];
    const float* b1 = (const float*)d_in[5];
    const float* W2 = (const float*)d_in[6];
    const float* b2 = (const float*)d_in[7];
    const float* W3 = (const float*)d_in[8];
    const float* b3 = (const float*)d_in[9];
    const float* W4 = (const float*)d_in[10];
    const float* b4 = (const float*)d_in[11];
    float* out = (float*)d_out;

    float* wsp = (float*)d_ws;
    float* P       = wsp;                            // 65536 floats
    float* Qp      = wsp + 65536;                    // 65536
    _Float16* nrh  = (_Float16*)(wsp + 131072);      // 65536 halves (32768 floats)
    _Float16* W3ph = (_Float16*)(wsp + 163840);      // 8192 halves (4096 floats)
    float* deg     = wsp + 167936;                   // 1024
    float* adapt   = wsp + 168960;                   // 524288; dyn partials overlay
    float* part    = adapt;                          // 196608 <= 524288

    prep_kernel<<<544, 256, 0, stream>>>(x, mask, W3, part, W3ph);
    node_kernel<<<B_ * N_, 64, 0, stream>>>(part, x, sc, W1, b1, W2, b2, W3, nrh, P, Qp);
    pair_mfma_kernel<<<512, 256, 0, stream>>>(nrh, P, Qp, W3ph, coords, b3, W4, b4, adapt, deg);
    norm_kernel<<<512, 256, 0, stream>>>(adapt, deg, out);
}